// Round 9
// baseline (129.246 us; speedup 1.0000x reference)
//
#include <hip/hip_runtime.h>
#include <math.h>

#define NROWS 65536   // B*T = 1024*64

typedef short bf16x8 __attribute__((ext_vector_type(8)));
typedef float f32x4  __attribute__((ext_vector_type(4)));

__device__ __forceinline__ unsigned short f2bf(float x){
    unsigned int u = __float_as_uint(x);
    u += 0x7FFFu + ((u >> 16) & 1u);      // RNE
    return (unsigned short)(u >> 16);
}

template<int CTRL, int RM>
__device__ __forceinline__ float dpp_add(float v){
    int m = __builtin_amdgcn_update_dpp(0, __float_as_int(v), CTRL, RM, 0xF, 1);
    return v + __int_as_float(m);
}
// sum within each 16-lane row; total lands in lane lm==15
__device__ __forceinline__ float rowsum16(float v){
    v = dpp_add<0x111, 0xF>(v);
    v = dpp_add<0x112, 0xF>(v);
    v = dpp_add<0x114, 0xF>(v);
    v = dpp_add<0x118, 0xF>(v);
    return v;
}
// butterfly over 8 lanes: all 8 lanes get the total
__device__ __forceinline__ float bfly8_add(float v){
    v = dpp_add<0xB1, 0xF>(v);     // quad_perm [1,0,3,2]
    v = dpp_add<0x4E, 0xF>(v);     // quad_perm [2,3,0,1]
    v = dpp_add<0x141, 0xF>(v);    // row_half_mirror
    return v;
}

// ---- prep: weights -> MFMA B-fragment order ----
__global__ __launch_bounds__(256) void prep_kernel(
    const float* __restrict__ W2, const float* __restrict__ W1,
    unsigned short* __restrict__ w2frag, unsigned short* __restrict__ w1frag)
{
    const int bx = blockIdx.x, t = threadIdx.x;
    if (bx < 128){
        const int ct = bx >> 3, kk = bx & 7;
        #pragma unroll
        for (int s = 0; s < 2; ++s){
            int f = t * 2 + s;
            int lane = f >> 3, e = f & 7;
            int k = kk * 32 + (lane >> 4) * 8 + e;
            int c = ct * 16 + (lane & 15);
            w2frag[(size_t)(ct * 8 + kk) * 512 + f] = f2bf(W2[k * 256 + c]);
        }
    } else {
        #pragma unroll
        for (int s = 0; s < 32; ++s){
            int flat = t * 32 + s;
            int ct = flat >> 9, r = flat & 511;
            int lane = r >> 3, e = r & 7;
            int k = (lane >> 4) * 8 + e;
            int c = ct * 16 + (lane & 15);
            w1frag[flat] = (k < 23) ? f2bf(W1[k * 256 + c]) : (unsigned short)0;
        }
    }
}

// ---- fused actor: 2048 blocks x 256 threads; block = 32 rows of one batch ----
// NOTE: no min-waves arg — (256,6) in r8 forced VGPR<64 and spilled (22 MB scratch
// writes); natural allocation is ~64 VGPR which already permits 8 waves/EU.
__global__ __launch_bounds__(256) void actor_kernel(
    const float* __restrict__ state, const float* __restrict__ noise,
    const float* __restrict__ Wq, const float* __restrict__ Wk,
    const float* __restrict__ Wv,
    const unsigned short* __restrict__ w1frag, const float* __restrict__ b1,
    const unsigned short* __restrict__ w2frag, const float* __restrict__ b2,
    const float* __restrict__ Wmu, const float* __restrict__ bmu,
    const float* __restrict__ Wls, const float* __restrict__ bls,
    float* __restrict__ action_out, float* __restrict__ logprob_out)
{
    // union A: {sLDS 576f, pjLDS 512f, qkLDS 544f} (6528 B) then h1LDS (16896 B)
    __shared__ __align__(16) unsigned char uniA[32 * 264 * 2];
    float* sLDS  = (float*)uniA;              // 64*9 (full batch)
    float* pjLDS = sLDS + 576;                // 64*8: s0..3, sn, cs (full batch)
    float* qkLDS = pjLDS + 512;               // 32*17 (own half)
    unsigned short* h1LDS = (unsigned short*)uniA;   // 32 x 264
    __shared__ __align__(16) unsigned short x0LDS[32 * 40];
    __shared__ float headLDS[4 * 32 * 5];

    const int t     = threadIdx.x;
    const int lane  = t & 63;
    const int w     = t >> 6;                 // 0..3
    const int lm    = lane & 15;
    const int lq    = lane >> 4;
    const int b     = blockIdx.x >> 1;
    const int ibase = (blockIdx.x & 1) * 32;  // own half rows [ibase, ibase+32)

    // ---- phase 0: load full-batch state (coalesced, 2 floats/thread) ----
    #pragma unroll
    for (int s = 0; s < 2; ++s){
        int idx = t + s * 256;
        float v = state[(size_t)b * 512 + idx];
        int r = idx >> 3, c = idx & 7;
        sLDS[r * 9 + c] = v;
        if (c < 4) pjLDS[r * 8 + c] = v;
    }
    __syncthreads();

    // ---- phase 0b: qk fold (96 thr, own half) + sincos (64 thr, full batch) ----
    if (t < 96){
        const int rloc = t & 31, h = t >> 5;
        const int row = ibase + rloc;
        float s[8];
        #pragma unroll
        for (int d = 0; d < 8; ++d) s[d] = sLDS[row * 9 + d];
        float q[5];
        #pragma unroll
        for (int e = 0; e < 5; ++e){
            int m = h * 5 + e;
            float acc = 0.f;
            #pragma unroll
            for (int d = 0; d < 8; ++d) acc += s[d] * Wq[d * 15 + m];
            q[e] = acc;
        }
        #pragma unroll
        for (int f = 0; f < 5; ++f){
            float acc = 0.f;
            #pragma unroll
            for (int kk = 0; kk < 5; ++kk) acc += Wk[f * 15 + h * 5 + kk] * q[kk];
            qkLDS[rloc * 17 + h * 5 + f] = acc * 0.64519834f;   // (1/sqrt5)*log2(e)
        }
    } else if (t < 160){
        const int row = t - 96;
        float ang = 1.5707963267948966f - sLDS[row * 9 + 7];
        float sn, cs;
        __sincosf(ang, &sn, &cs);
        pjLDS[row * 8 + 4] = sn;
        pjLDS[row * 8 + 5] = cs;
    }
    __syncthreads();

    // ---- phase 1: attention, single pass (scores bounded, softmax scale-free).
    //      wave w owns i_loc = w*8+il; each 8-lane group covers all 64 j ----
    {
        const int il = lane >> 3;
        const int js = lane & 7;
        const int iloc = w * 8 + il;
        const int i = ibase + iloc;
        const float si0 = sLDS[i * 9 + 0], si1 = sLDS[i * 9 + 1];
        const float si2 = sLDS[i * 9 + 2], si3 = sLDS[i * 9 + 3];
        float qkv[15];
        #pragma unroll
        for (int m = 0; m < 15; ++m) qkv[m] = qkLDS[iloc * 17 + m];

        float s0 = 0.f, s1 = 0.f, s2 = 0.f;
        float g0[5] = {0,0,0,0,0}, g1[5] = {0,0,0,0,0}, g2[5] = {0,0,0,0,0};
        #pragma unroll
        for (int jj = 0; jj < 8; ++jj){
            const int j = jj * 8 + js;
            float4 pj = *(const float4*)&pjLDS[j * 8];
            float sn = pjLDS[j * 8 + 4], cs = pjLDS[j * 8 + 5];
            float d0 = pj.x - si0, d1 = pj.y - si1, d2 = pj.z - si2, d3 = pj.w - si3;
            float xn0 = d0 * cs - d1 * sn, yn0 = d0 * sn + d1 * cs;
            float xn1 = d2 * cs - d3 * sn, yn1 = d2 * sn + d3 * cs;
            float r2v = xn0 * xn0 + yn0 * yn0;
            bool self = (j == i);
            float inv_r = self ? 0.f : rsqrtf(r2v);
            float rv = r2v * inv_r;
            float ex = exp2f(rv * 7.2134752f - 2.8853901f);   // e^(5r-2)
            float f4 = 1.f / (1.f + ex);
            float f0 = xn0 * inv_r, f1 = yn0 * inv_r;
            float sc0 = f0*qkv[0]  + f1*qkv[1]  + xn1*qkv[2]  + yn1*qkv[3]  + f4*qkv[4];
            float sc1 = f0*qkv[5]  + f1*qkv[6]  + xn1*qkv[7]  + yn1*qkv[8]  + f4*qkv[9];
            float sc2 = f0*qkv[10] + f1*qkv[11] + xn1*qkv[12] + yn1*qkv[13] + f4*qkv[14];
            float e0 = self ? 0.f : exp2f(sc0);
            float e1 = self ? 0.f : exp2f(sc1);
            float e2 = self ? 0.f : exp2f(sc2);
            s0 += e0; s1 += e1; s2 += e2;
            g0[0] += e0*f0; g0[1] += e0*f1; g0[2] += e0*xn1; g0[3] += e0*yn1; g0[4] += e0*f4;
            g1[0] += e1*f0; g1[1] += e1*f1; g1[2] += e1*xn1; g1[3] += e1*yn1; g1[4] += e1*f4;
            g2[0] += e2*f0; g2[1] += e2*f1; g2[2] += e2*xn1; g2[3] += e2*yn1; g2[4] += e2*f4;
        }
        s0 = bfly8_add(s0); s1 = bfly8_add(s1); s2 = bfly8_add(s2);
        #pragma unroll
        for (int f = 0; f < 5; ++f){
            g0[f] = bfly8_add(g0[f]);
            g1[f] = bfly8_add(g1[f]);
            g2[f] = bfly8_add(g2[f]);
        }
        float i0 = 1.f / s0, i1 = 1.f / s1, i2 = 1.f / s2;

        // x0: att cols (lane js writes m = 2js, 2js+1), state cols, zero pad
        #pragma unroll
        for (int mm = 0; mm < 2; ++mm){
            int m = js * 2 + mm;
            if (m < 15){
                float G0 = (m < 5) ? g0[0] : (m < 10) ? g1[0] : g2[0];
                float G1 = (m < 5) ? g0[1] : (m < 10) ? g1[1] : g2[1];
                float G2 = (m < 5) ? g0[2] : (m < 10) ? g1[2] : g2[2];
                float G3 = (m < 5) ? g0[3] : (m < 10) ? g1[3] : g2[3];
                float G4 = (m < 5) ? g0[4] : (m < 10) ? g1[4] : g2[4];
                float I  = (m < 5) ? i0    : (m < 10) ? i1    : i2;
                float av = (G0 * Wv[m] + G1 * Wv[15 + m] + G2 * Wv[30 + m]
                          + G3 * Wv[45 + m] + G4 * Wv[60 + m]) * I;
                x0LDS[iloc * 40 + m] = f2bf(av);
            }
        }
        x0LDS[iloc * 40 + 15 + js] = f2bf(sLDS[i * 9 + js]);
        x0LDS[iloc * 40 + 23 + js] = 0;
        if (js == 0) x0LDS[iloc * 40 + 31] = 0;
    }
    __syncthreads();

    // ---- phase 2: h1 = relu(x0 @ W1 + b1); wave w owns coltiles 4w..4w+3 ----
    {
        bf16x8 afr[2];
        #pragma unroll
        for (int rt = 0; rt < 2; ++rt)
            afr[rt] = *(const bf16x8*)&x0LDS[(rt * 16 + lm) * 40 + lq * 8];
        // h1LDS overlays sLDS/pjLDS/qkLDS — all dead after phase-1 barrier
        #pragma unroll
        for (int ci = 0; ci < 4; ++ci){
            const int ct = w * 4 + ci;
            bf16x8 bfr = *(const bf16x8*)&w1frag[(size_t)ct * 512 + lane * 8];
            float bb = b1[ct * 16 + lm];
            #pragma unroll
            for (int rt = 0; rt < 2; ++rt){
                f32x4 c0 = {0.f, 0.f, 0.f, 0.f};
                c0 = __builtin_amdgcn_mfma_f32_16x16x32_bf16(afr[rt], bfr, c0, 0, 0, 0);
                #pragma unroll
                for (int p = 0; p < 4; ++p)
                    h1LDS[(rt * 16 + lq * 4 + p) * 264 + ct * 16 + lm] = f2bf(fmaxf(c0[p] + bb, 0.f));
            }
        }
    }
    __syncthreads();

    // ---- phase 3: h2 = relu(h1 @ W2 + b2); heads in-register ----
    {
        f32x4 acc[2][4];
        #pragma unroll
        for (int rt = 0; rt < 2; ++rt)
            #pragma unroll
            for (int ci = 0; ci < 4; ++ci) acc[rt][ci] = (f32x4){0.f, 0.f, 0.f, 0.f};

        #pragma unroll
        for (int kk = 0; kk < 8; ++kk){
            bf16x8 arf[2], brf[4];
            #pragma unroll
            for (int rt = 0; rt < 2; ++rt)
                arf[rt] = *(const bf16x8*)&h1LDS[(rt * 16 + lm) * 264 + kk * 32 + lq * 8];
            #pragma unroll
            for (int ci = 0; ci < 4; ++ci)
                brf[ci] = *(const bf16x8*)&w2frag[(size_t)((w * 4 + ci) * 8 + kk) * 512 + lane * 8];
            #pragma unroll
            for (int rt = 0; rt < 2; ++rt)
                #pragma unroll
                for (int ci = 0; ci < 4; ++ci)
                    acc[rt][ci] = __builtin_amdgcn_mfma_f32_16x16x32_bf16(arf[rt], brf[ci], acc[rt][ci], 0, 0, 0);
        }

        float bb[4];
        float2 wm[4], wl[4];
        #pragma unroll
        for (int ci = 0; ci < 4; ++ci){
            int c = (w * 4 + ci) * 16 + lm;
            bb[ci] = b2[c];
            wm[ci] = *(const float2*)&Wmu[c * 2];
            wl[ci] = *(const float2*)&Wls[c * 2];
        }
        #pragma unroll
        for (int rt = 0; rt < 2; ++rt){
            #pragma unroll
            for (int p = 0; p < 4; ++p){
                float m0 = 0.f, m1 = 0.f, l0 = 0.f, l1 = 0.f;
                #pragma unroll
                for (int ci = 0; ci < 4; ++ci){
                    float hv = fmaxf(acc[rt][ci][p] + bb[ci], 0.f);
                    m0 += hv * wm[ci].x;
                    m1 += hv * wm[ci].y;
                    l0 += hv * wl[ci].x;
                    l1 += hv * wl[ci].y;
                }
                m0 = rowsum16(m0); m1 = rowsum16(m1);
                l0 = rowsum16(l0); l1 = rowsum16(l1);
                if (lm == 15){
                    int row = rt * 16 + lq * 4 + p;
                    float* hp = &headLDS[(w * 32 + row) * 5];
                    hp[0] = m0; hp[1] = m1; hp[2] = l0; hp[3] = l1;
                }
            }
        }
    }
    __syncthreads();

    // ---- phase 4: epilogue, 32 threads = 32 rows ----
    if (t < 32){
        const int row = t;
        float m0 = 0.f, m1 = 0.f, l0 = 0.f, l1 = 0.f;
        #pragma unroll
        for (int ww = 0; ww < 4; ++ww){
            const float* hp = &headLDS[(ww * 32 + row) * 5];
            m0 += hp[0]; m1 += hp[1]; l0 += hp[2]; l1 += hp[3];
        }
        const size_t grow = (size_t)b * 64 + ibase + row;
        float n0 = noise[grow * 2 + 0];
        float n1 = noise[grow * 2 + 1];
        float lp = 0.f;
        {
            float mu = tanhf(m0 + bmu[0]);
            float ls = tanhf(l0 + bls[0]);
            ls = -20.f + 11.f * (ls + 1.f);
            float sd = expf(ls);
            float a = tanhf(mu + sd * n0);
            action_out[grow * 2 + 0] = a;
            lp += -0.5f * n0 * n0 - ls - 0.9189385332046727f - logf(1.f - a * a + 1e-7f);
        }
        {
            float mu = tanhf(m1 + bmu[1]);
            float ls = tanhf(l1 + bls[1]);
            ls = -20.f + 11.f * (ls + 1.f);
            float sd = expf(ls);
            float a = tanhf(mu + sd * n1);
            action_out[grow * 2 + 1] = a;
            lp += -0.5f * n1 * n1 - ls - 0.9189385332046727f - logf(1.f - a * a + 1e-7f);
        }
        logprob_out[grow] = lp;
    }
}

extern "C" void kernel_launch(void* const* d_in, const int* in_sizes, int n_in,
                              void* d_out, int out_size, void* d_ws, size_t ws_size,
                              hipStream_t stream)
{
    (void)in_sizes; (void)n_in; (void)out_size; (void)ws_size;
    const float* state = (const float*)d_in[0];
    const float* noise = (const float*)d_in[1];
    const float* Wq  = (const float*)d_in[2];
    const float* Wk  = (const float*)d_in[3];
    const float* Wv  = (const float*)d_in[4];
    const float* W1  = (const float*)d_in[5];
    const float* b1  = (const float*)d_in[6];
    const float* W2  = (const float*)d_in[7];
    const float* b2  = (const float*)d_in[8];
    const float* Wmu = (const float*)d_in[9];
    const float* bmu = (const float*)d_in[10];
    const float* Wls = (const float*)d_in[11];
    const float* bls = (const float*)d_in[12];

    unsigned short* w2frag = (unsigned short*)d_ws;   // 65536 bf16
    unsigned short* w1frag = w2frag + 65536;          // 8192 bf16

    float* action_out  = (float*)d_out;
    float* logprob_out = (float*)d_out + (size_t)NROWS * 2;

    prep_kernel<<<129, 256, 0, stream>>>(W2, W1, w2frag, w1frag);
    actor_kernel<<<2048, 256, 0, stream>>>(state, noise, Wq, Wk, Wv,
        w1frag, b1, w2frag, b2, Wmu, bmu, Wls, bls, action_out, logprob_out);
}

// Round 10
// 119.922 us; speedup vs baseline: 1.0778x; 1.0778x over previous
//
#include <hip/hip_runtime.h>
#include <math.h>

#define NROWS 65536   // B*T = 1024*64

typedef short bf16x8 __attribute__((ext_vector_type(8)));
typedef float f32x4  __attribute__((ext_vector_type(4)));
typedef float f32x2  __attribute__((ext_vector_type(2)));

__device__ __forceinline__ unsigned short f2bf(float x){
    unsigned int u = __float_as_uint(x);
    u += 0x7FFFu + ((u >> 16) & 1u);      // RNE
    return (unsigned short)(u >> 16);
}
__device__ __forceinline__ f32x2 sp2(float x){ return (f32x2){x, x}; }

template<int CTRL, int RM>
__device__ __forceinline__ float dpp_add(float v){
    int m = __builtin_amdgcn_update_dpp(0, __float_as_int(v), CTRL, RM, 0xF, 1);
    return v + __int_as_float(m);
}
// sum within each 16-lane row; total lands in lane lm==15
__device__ __forceinline__ float rowsum16(float v){
    v = dpp_add<0x111, 0xF>(v);
    v = dpp_add<0x112, 0xF>(v);
    v = dpp_add<0x114, 0xF>(v);
    v = dpp_add<0x118, 0xF>(v);
    return v;
}
// butterfly over 8 lanes: all 8 lanes get the total
__device__ __forceinline__ float bfly8_add(float v){
    v = dpp_add<0xB1, 0xF>(v);     // quad_perm [1,0,3,2]
    v = dpp_add<0x4E, 0xF>(v);     // quad_perm [2,3,0,1]
    v = dpp_add<0x141, 0xF>(v);    // row_half_mirror
    return v;
}

// ---- prep: weights -> MFMA B-fragment order ----
__global__ __launch_bounds__(256) void prep_kernel(
    const float* __restrict__ W2, const float* __restrict__ W1,
    unsigned short* __restrict__ w2frag, unsigned short* __restrict__ w1frag)
{
    const int bx = blockIdx.x, t = threadIdx.x;
    if (bx < 128){
        const int ct = bx >> 3, kk = bx & 7;
        #pragma unroll
        for (int s = 0; s < 2; ++s){
            int f = t * 2 + s;
            int lane = f >> 3, e = f & 7;
            int k = kk * 32 + (lane >> 4) * 8 + e;
            int c = ct * 16 + (lane & 15);
            w2frag[(size_t)(ct * 8 + kk) * 512 + f] = f2bf(W2[k * 256 + c]);
        }
    } else {
        #pragma unroll
        for (int s = 0; s < 32; ++s){
            int flat = t * 32 + s;
            int ct = flat >> 9, r = flat & 511;
            int lane = r >> 3, e = r & 7;
            int k = (lane >> 4) * 8 + e;
            int c = ct * 16 + (lane & 15);
            w1frag[flat] = (k < 23) ? f2bf(W1[k * 256 + c]) : (unsigned short)0;
        }
    }
}

// ---- fused actor: one block per batch, 512 threads (r7 config — best measured).
//      Phase 1 processes 2 j's per iter as float2 (targets v_pk_fma_f32). ----
__global__ __launch_bounds__(512, 4) void actor_kernel(
    const float* __restrict__ state, const float* __restrict__ noise,
    const float* __restrict__ Wq, const float* __restrict__ Wk,
    const float* __restrict__ Wv,
    const unsigned short* __restrict__ w1frag, const float* __restrict__ b1,
    const unsigned short* __restrict__ w2frag, const float* __restrict__ b2,
    const float* __restrict__ Wmu, const float* __restrict__ bmu,
    const float* __restrict__ Wls, const float* __restrict__ bls,
    float* __restrict__ action_out, float* __restrict__ logprob_out)
{
    // union A: {sLDS 576f, pjLDS 384f (paired SoA), qkLDS 1088f} then h1LDS (33792 B)
    __shared__ __align__(16) unsigned char uniA[64 * 264 * 2];
    float* sLDS  = (float*)uniA;              // 64*9
    float* pjLDS = sLDS + 576;                // 32*12: pairs (c(j), c(j+32)) for c=s0..3,sn,cs
    float* qkLDS = pjLDS + 384;               // 64*17 prescaled qk
    unsigned short* h1LDS = (unsigned short*)uniA;   // 64 x 264 (stride 264)
    __shared__ __align__(16) unsigned short x0LDS[64 * 40];
    __shared__ float headLDS[8 * 64 * 5];

    const int t    = threadIdx.x;
    const int lane = t & 63;
    const int w    = t >> 6;                  // 0..7
    const int lm   = lane & 15;
    const int lq   = lane >> 4;
    const int b    = blockIdx.x;

    // ---- phase 0: load state (coalesced) ----
    {
        float v = state[(size_t)b * 512 + t];
        int r = t >> 3, c = t & 7;
        sLDS[r * 9 + c] = v;
        if (c < 4) pjLDS[(r & 31) * 12 + c * 2 + (r >> 5)] = v;
    }
    __syncthreads();

    // ---- phase 0b: qk fold (192 thr) + sincos (wave 7) ----
    if (t < 192){
        const int row = t & 63, h = t >> 6;
        float s[8];
        #pragma unroll
        for (int d = 0; d < 8; ++d) s[d] = sLDS[row * 9 + d];
        float q[5];
        #pragma unroll
        for (int e = 0; e < 5; ++e){
            int m = h * 5 + e;
            float acc = 0.f;
            #pragma unroll
            for (int d = 0; d < 8; ++d) acc += s[d] * Wq[d * 15 + m];
            q[e] = acc;
        }
        #pragma unroll
        for (int f = 0; f < 5; ++f){
            float acc = 0.f;
            #pragma unroll
            for (int kk = 0; kk < 5; ++kk) acc += Wk[f * 15 + h * 5 + kk] * q[kk];
            qkLDS[row * 17 + h * 5 + f] = acc * 0.64519834f;   // (1/sqrt5)*log2(e)
        }
    } else if (w == 7){
        const int row = lane;
        float ang = 1.5707963267948966f - sLDS[row * 9 + 7];
        float sn, cs;
        __sincosf(ang, &sn, &cs);
        int base = (row & 31) * 12 + (row >> 5);
        pjLDS[base + 8]  = sn;
        pjLDS[base + 10] = cs;
    }
    __syncthreads();

    // ---- phase 1: attention, single pass, 2 j's per iter via packed fp32.
    //      wave w owns i = w*8+il; 8-lane group covers all 64 j (4 x 2) ----
    {
        const int il = lane >> 3;
        const int js = lane & 7;
        const int i  = w * 8 + il;
        const float si0 = sLDS[i * 9 + 0], si1 = sLDS[i * 9 + 1];
        const float si2 = sLDS[i * 9 + 2], si3 = sLDS[i * 9 + 3];
        float qkv[15];
        #pragma unroll
        for (int m = 0; m < 15; ++m) qkv[m] = qkLDS[i * 17 + m];   // group-broadcast

        f32x2 s0 = {0.f,0.f}, s1 = {0.f,0.f}, s2 = {0.f,0.f};
        f32x2 g0[5], g1[5], g2[5];
        #pragma unroll
        for (int f = 0; f < 5; ++f){ g0[f] = sp2(0.f); g1[f] = sp2(0.f); g2[f] = sp2(0.f); }

        #pragma unroll
        for (int jj = 0; jj < 4; ++jj){
            const int jb = jj * 8 + js;                  // handles j = jb and jb+32
            const f32x2* pp = (const f32x2*)&pjLDS[jb * 12];
            f32x2 p0 = pp[0], p1 = pp[1], p2 = pp[2], p3 = pp[3];
            f32x2 sn = pp[4], cs = pp[5];
            f32x2 d0 = p0 - sp2(si0), d1 = p1 - sp2(si1);
            f32x2 d2 = p2 - sp2(si2), d3 = p3 - sp2(si3);
            f32x2 xn0 = d0 * cs - d1 * sn, yn0 = d0 * sn + d1 * cs;
            f32x2 xn1 = d2 * cs - d3 * sn, yn1 = d2 * sn + d3 * cs;
            f32x2 r2v = xn0 * xn0 + yn0 * yn0;
            const bool self0 = (jb == i), self1 = (jb + 32 == i);
            f32x2 inv_r;
            inv_r.x = self0 ? 0.f : rsqrtf(r2v.x);
            inv_r.y = self1 ? 0.f : rsqrtf(r2v.y);
            f32x2 rv  = r2v * inv_r;
            f32x2 arg = rv * sp2(7.2134752f) - sp2(2.8853901f);   // log2(e)*(5r-2)
            f32x2 ex; ex.x = exp2f(arg.x); ex.y = exp2f(arg.y);
            f32x2 f4; f4.x = 1.f / (1.f + ex.x); f4.y = 1.f / (1.f + ex.y);
            f32x2 f0 = xn0 * inv_r, f1 = yn0 * inv_r;
            f32x2 sc0 = f0*sp2(qkv[0])  + f1*sp2(qkv[1])  + xn1*sp2(qkv[2])  + yn1*sp2(qkv[3])  + f4*sp2(qkv[4]);
            f32x2 sc1 = f0*sp2(qkv[5])  + f1*sp2(qkv[6])  + xn1*sp2(qkv[7])  + yn1*sp2(qkv[8])  + f4*sp2(qkv[9]);
            f32x2 sc2 = f0*sp2(qkv[10]) + f1*sp2(qkv[11]) + xn1*sp2(qkv[12]) + yn1*sp2(qkv[13]) + f4*sp2(qkv[14]);
            f32x2 e0, e1, e2;
            e0.x = self0 ? 0.f : exp2f(sc0.x);  e0.y = self1 ? 0.f : exp2f(sc0.y);
            e1.x = self0 ? 0.f : exp2f(sc1.x);  e1.y = self1 ? 0.f : exp2f(sc1.y);
            e2.x = self0 ? 0.f : exp2f(sc2.x);  e2.y = self1 ? 0.f : exp2f(sc2.y);
            s0 += e0; s1 += e1; s2 += e2;
            g0[0] += e0*f0; g0[1] += e0*f1; g0[2] += e0*xn1; g0[3] += e0*yn1; g0[4] += e0*f4;
            g1[0] += e1*f0; g1[1] += e1*f1; g1[2] += e1*xn1; g1[3] += e1*yn1; g1[4] += e1*f4;
            g2[0] += e2*f0; g2[1] += e2*f1; g2[2] += e2*xn1; g2[3] += e2*yn1; g2[4] += e2*f4;
        }
        // collapse pair lanes, then 8-lane butterfly
        float S0 = s0.x + s0.y, S1 = s1.x + s1.y, S2 = s2.x + s2.y;
        float G0[5], G1[5], G2[5];
        #pragma unroll
        for (int f = 0; f < 5; ++f){
            G0[f] = bfly8_add(g0[f].x + g0[f].y);
            G1[f] = bfly8_add(g1[f].x + g1[f].y);
            G2[f] = bfly8_add(g2[f].x + g2[f].y);
        }
        S0 = bfly8_add(S0); S1 = bfly8_add(S1); S2 = bfly8_add(S2);
        float i0 = 1.f / S0, i1 = 1.f / S1, i2 = 1.f / S2;

        // x0: att cols (lane js writes m = 2js, 2js+1), state cols, zero pad
        #pragma unroll
        for (int mm = 0; mm < 2; ++mm){
            int m = js * 2 + mm;
            if (m < 15){
                float A0 = (m < 5) ? G0[0] : (m < 10) ? G1[0] : G2[0];
                float A1 = (m < 5) ? G0[1] : (m < 10) ? G1[1] : G2[1];
                float A2 = (m < 5) ? G0[2] : (m < 10) ? G1[2] : G2[2];
                float A3 = (m < 5) ? G0[3] : (m < 10) ? G1[3] : G2[3];
                float A4 = (m < 5) ? G0[4] : (m < 10) ? G1[4] : G2[4];
                float I  = (m < 5) ? i0    : (m < 10) ? i1    : i2;
                float av = (A0 * Wv[m] + A1 * Wv[15 + m] + A2 * Wv[30 + m]
                          + A3 * Wv[45 + m] + A4 * Wv[60 + m]) * I;
                x0LDS[i * 40 + m] = f2bf(av);
            }
        }
        x0LDS[i * 40 + 15 + js] = f2bf(sLDS[i * 9 + js]);
        x0LDS[i * 40 + 23 + js] = 0;
        if (js == 0) x0LDS[i * 40 + 31] = 0;
    }
    __syncthreads();

    // ---- phase 2: h1 = relu(x0 @ W1 + b1); wave w owns coltiles 2w, 2w+1 ----
    {
        bf16x8 afr[4];
        #pragma unroll
        for (int rt = 0; rt < 4; ++rt)
            afr[rt] = *(const bf16x8*)&x0LDS[(rt * 16 + lm) * 40 + lq * 8];
        // h1LDS overlays sLDS/pjLDS/qkLDS — all dead after phase-1 barrier
        #pragma unroll
        for (int ci = 0; ci < 2; ++ci){
            const int ct = w * 2 + ci;
            bf16x8 bfr = *(const bf16x8*)&w1frag[(size_t)ct * 512 + lane * 8];
            float bb = b1[ct * 16 + lm];
            #pragma unroll
            for (int rt = 0; rt < 4; ++rt){
                f32x4 c0 = {0.f, 0.f, 0.f, 0.f};
                c0 = __builtin_amdgcn_mfma_f32_16x16x32_bf16(afr[rt], bfr, c0, 0, 0, 0);
                #pragma unroll
                for (int p = 0; p < 4; ++p)
                    h1LDS[(rt * 16 + lq * 4 + p) * 264 + ct * 16 + lm] = f2bf(fmaxf(c0[p] + bb, 0.f));
            }
        }
    }
    __syncthreads();

    // ---- phase 3: h2 = relu(h1 @ W2 + b2); heads in-register ----
    {
        f32x4 acc[4][2];
        #pragma unroll
        for (int rt = 0; rt < 4; ++rt)
            #pragma unroll
            for (int ci = 0; ci < 2; ++ci) acc[rt][ci] = (f32x4){0.f, 0.f, 0.f, 0.f};

        #pragma unroll
        for (int kk = 0; kk < 8; ++kk){
            bf16x8 arf[4], brf[2];
            #pragma unroll
            for (int rt = 0; rt < 4; ++rt)
                arf[rt] = *(const bf16x8*)&h1LDS[(rt * 16 + lm) * 264 + kk * 32 + lq * 8];
            #pragma unroll
            for (int ci = 0; ci < 2; ++ci)
                brf[ci] = *(const bf16x8*)&w2frag[(size_t)((w * 2 + ci) * 8 + kk) * 512 + lane * 8];
            #pragma unroll
            for (int rt = 0; rt < 4; ++rt)
                #pragma unroll
                for (int ci = 0; ci < 2; ++ci)
                    acc[rt][ci] = __builtin_amdgcn_mfma_f32_16x16x32_bf16(arf[rt], brf[ci], acc[rt][ci], 0, 0, 0);
        }

        float bb[2];
        float2 wm[2], wl[2];
        #pragma unroll
        for (int ci = 0; ci < 2; ++ci){
            int c = (w * 2 + ci) * 16 + lm;
            bb[ci] = b2[c];
            wm[ci] = *(const float2*)&Wmu[c * 2];
            wl[ci] = *(const float2*)&Wls[c * 2];
        }
        #pragma unroll
        for (int rt = 0; rt < 4; ++rt){
            #pragma unroll
            for (int p = 0; p < 4; ++p){
                float m0 = 0.f, m1 = 0.f, l0 = 0.f, l1 = 0.f;
                #pragma unroll
                for (int ci = 0; ci < 2; ++ci){
                    float hv = fmaxf(acc[rt][ci][p] + bb[ci], 0.f);
                    m0 += hv * wm[ci].x;
                    m1 += hv * wm[ci].y;
                    l0 += hv * wl[ci].x;
                    l1 += hv * wl[ci].y;
                }
                m0 = rowsum16(m0); m1 = rowsum16(m1);
                l0 = rowsum16(l0); l1 = rowsum16(l1);
                if (lm == 15){
                    int row = rt * 16 + lq * 4 + p;
                    float* hp = &headLDS[(w * 64 + row) * 5];
                    hp[0] = m0; hp[1] = m1; hp[2] = l0; hp[3] = l1;
                }
            }
        }
    }
    __syncthreads();

    // ---- phase 4: epilogue, 64 threads = 64 rows ----
    if (t < 64){
        const int row = t;
        float m0 = 0.f, m1 = 0.f, l0 = 0.f, l1 = 0.f;
        #pragma unroll
        for (int ww = 0; ww < 8; ++ww){
            const float* hp = &headLDS[(ww * 64 + row) * 5];
            m0 += hp[0]; m1 += hp[1]; l0 += hp[2]; l1 += hp[3];
        }
        const size_t grow = (size_t)b * 64 + row;
        float n0 = noise[grow * 2 + 0];
        float n1 = noise[grow * 2 + 1];
        float lp = 0.f;
        {
            float mu = tanhf(m0 + bmu[0]);
            float ls = tanhf(l0 + bls[0]);
            ls = -20.f + 11.f * (ls + 1.f);
            float sd = expf(ls);
            float a = tanhf(mu + sd * n0);
            action_out[grow * 2 + 0] = a;
            lp += -0.5f * n0 * n0 - ls - 0.9189385332046727f - logf(1.f - a * a + 1e-7f);
        }
        {
            float mu = tanhf(m1 + bmu[1]);
            float ls = tanhf(l1 + bls[1]);
            ls = -20.f + 11.f * (ls + 1.f);
            float sd = expf(ls);
            float a = tanhf(mu + sd * n1);
            action_out[grow * 2 + 1] = a;
            lp += -0.5f * n1 * n1 - ls - 0.9189385332046727f - logf(1.f - a * a + 1e-7f);
        }
        logprob_out[grow] = lp;
    }
}

extern "C" void kernel_launch(void* const* d_in, const int* in_sizes, int n_in,
                              void* d_out, int out_size, void* d_ws, size_t ws_size,
                              hipStream_t stream)
{
    (void)in_sizes; (void)n_in; (void)out_size; (void)ws_size;
    const float* state = (const float*)d_in[0];
    const float* noise = (const float*)d_in[1];
    const float* Wq  = (const float*)d_in[2];
    const float* Wk  = (const float*)d_in[3];
    const float* Wv  = (const float*)d_in[4];
    const float* W1  = (const float*)d_in[5];
    const float* b1  = (const float*)d_in[6];
    const float* W2  = (const float*)d_in[7];
    const float* b2  = (const float*)d_in[8];
    const float* Wmu = (const float*)d_in[9];
    const float* bmu = (const float*)d_in[10];
    const float* Wls = (const float*)d_in[11];
    const float* bls = (const float*)d_in[12];

    unsigned short* w2frag = (unsigned short*)d_ws;   // 65536 bf16
    unsigned short* w1frag = w2frag + 65536;          // 8192 bf16

    float* action_out  = (float*)d_out;
    float* logprob_out = (float*)d_out + (size_t)NROWS * 2;

    prep_kernel<<<129, 256, 0, stream>>>(W2, W1, w2frag, w1frag);
    actor_kernel<<<1024, 512, 0, stream>>>(state, noise, Wq, Wk, Wv,
        w1frag, b1, w2frag, b2, Wmu, bmu, Wls, bls, action_out, logprob_out);
}